// Round 5
// baseline (305.198 us; speedup 1.0000x reference)
//
#include <hip/hip_runtime.h>

// Bisect round: pure fp32 VALU implementation — no MFMA, no bf16, no vector-ext
// types. One block = one batch. Stage combined [27][128] fp32 into LDS, each
// of 351 threads computes one strict-upper-triangle pair dot product.

constexpr int kRows  = 27;
constexpr int kD     = 128;
constexpr int kPitch = 132;   // fp32 LDS row pitch (128+4) to spread banks across rows
constexpr int kPairs = 351;   // 27*26/2

__global__ void interact_fp32_kernel(
    const float* __restrict__ sparse_x,   // [B][26][128] fp32
    const float* __restrict__ dense_x,    // [B][128] fp32
    float* __restrict__ out)              // [B][351] fp32
{
    __shared__ float X[kRows * kPitch];   // 27*132*4 = 14,256 B
    const int t = threadIdx.x;            // block = 384 threads (6 waves)
    const int b = blockIdx.x;

    // ---- Stage: 27*128 = 3456 floats = 864 float4, coalesced per source region.
    for (int e = t; e < 864; e += 384) {
        const int f   = e * 4;
        const int row = f >> 7;
        const int col = f & 127;
        float4 v;
        if (row < 26) {
            v = *reinterpret_cast<const float4*>(sparse_x + (size_t)b * (26 * kD) + f);
        } else {
            v = *reinterpret_cast<const float4*>(dense_x + (size_t)b * kD + col);
        }
        *reinterpret_cast<float4*>(&X[row * kPitch + col]) = v;
    }
    __syncthreads();

    // ---- Compute: thread p < 351 handles pair (i, j), i < j.
    if (t < kPairs) {
        // decode p -> (i, j): p = i*(53-i)/2 + (j-i-1)
        int p = t, i = 0;
        while (p >= (26 - i)) { p -= (26 - i); ++i; }
        const int j = i + 1 + p;

        const float* ri = &X[i * kPitch];
        const float* rj = &X[j * kPitch];
        float acc = 0.f;
        #pragma unroll
        for (int d4 = 0; d4 < kD / 4; ++d4) {
            float4 a = *reinterpret_cast<const float4*>(ri + d4 * 4);
            float4 c = *reinterpret_cast<const float4*>(rj + d4 * 4);
            acc += a.x * c.x + a.y * c.y + a.z * c.z + a.w * c.w;
        }
        out[(size_t)b * kPairs + t] = acc;
    }
}

extern "C" void kernel_launch(void* const* d_in, const int* in_sizes, int n_in,
                              void* d_out, int out_size, void* d_ws, size_t ws_size,
                              hipStream_t stream) {
    const float* sparse_x = (const float*)d_in[0];
    const float* dense_x  = (const float*)d_in[1];
    float* out = (float*)d_out;
    const int B = in_sizes[1] / kD;       // 16384
    interact_fp32_kernel<<<B, 384, 0, stream>>>(sparse_x, dense_x, out);
}

// Round 6
// 304.518 us; speedup vs baseline: 1.0022x; 1.0022x over previous
//
#include <hip/hip_runtime.h>

// Problem constants (reference: F=26, D=128, B=16384, rows = F+1 = 27)
constexpr int kRows   = 27;
constexpr int kD      = 128;
constexpr int kKP     = 136;            // LDS row pitch in bf16 elems; 136 => fragment b128 reads hit all 32 banks evenly
constexpr int kSlot   = 32 * kKP;       // shorts per batch slot (rows padded to 32 for MFMA)
constexpr int kNB     = 4;              // batches per block (one per wave)
constexpr int kPairs  = 351;            // 27*26/2

typedef __attribute__((ext_vector_type(8))) short bf16x8;   // 8 bf16 = 4 VGPRs (MFMA A/B fragment)
typedef __attribute__((ext_vector_type(4))) float f32x4;    // MFMA 16x16 accumulator

__device__ __forceinline__ unsigned short to_bf16(float f) {
    union { float f; unsigned u; } x; x.f = f;
    unsigned u = x.u;
    return (unsigned short)((u + 0x7fffu + ((u >> 16) & 1u)) >> 16);  // round-to-nearest-even
}

__device__ __forceinline__ int triu_idx(int i, int j) {
    // row-major strict upper triangle of 27x27: k = i*(53-i)/2 + (j-i-1)
    return (i * (53 - i)) / 2 + (j - i - 1);
}

__global__ __launch_bounds__(256) void interact_kernel(
    const float* __restrict__ sparse_x,   // [B][26][128] fp32
    const float* __restrict__ dense_x,    // [B][128] fp32
    float* __restrict__ out)              // [B][351] fp32
{
    __shared__ short lds[kNB * kSlot];    // 4 * 4352 * 2 B = 34,816 B -> 4 blocks/CU (LDS-limited)
    const int t  = threadIdx.x;
    const int b0 = blockIdx.x * kNB;

    // ---- Zero MFMA pad rows 27..31 (cols 0..127) so no lane ever reads uninitialized LDS.
    // 4 slots * 5 rows * 32 ushort4 = 640 stores over 256 threads.
    {
        const ushort4 z = {0, 0, 0, 0};
        #pragma unroll
        for (int e = t; e < 640; e += 256) {
            const int slot = e / 160;           // 160 = 5 rows * 32 vec4 per slot
            const int rem  = e - slot * 160;
            const int row  = 27 + (rem >> 5);
            const int c4   = (rem & 31) * 4;
            *reinterpret_cast<ushort4*>(&lds[slot * kSlot + row * kKP + c4]) = z;
        }
    }

    // ---- Stage sparse rows: 4 batches * 26 * 128 = 13312 floats = 3328 float4 = 13/thread, fully coalesced
    const float4* sp = reinterpret_cast<const float4*>(sparse_x + (size_t)b0 * (26 * kD));
    #pragma unroll
    for (int it = 0; it < 13; ++it) {
        const int e = t + it * 256;
        float4 v = sp[e];
        const int f    = e * 4;
        const int slot = f / 3328;              // 3328 = 26*128 floats per batch
        const int rem  = f - slot * 3328;
        const int row  = rem >> 7;
        const int col  = rem & 127;
        ushort4 h;
        h.x = to_bf16(v.x); h.y = to_bf16(v.y);
        h.z = to_bf16(v.z); h.w = to_bf16(v.w);
        *reinterpret_cast<ushort4*>(&lds[slot * kSlot + row * kKP + col]) = h;
    }
    // ---- Stage dense rows into row 26 of each slot: 4*128 floats = 128 float4
    if (t < 32 * kNB) {
        const int slot = t >> 5;
        const int c4   = (t & 31) * 4;
        float4 v = *reinterpret_cast<const float4*>(dense_x + (size_t)(b0 + slot) * kD + c4);
        ushort4 h;
        h.x = to_bf16(v.x); h.y = to_bf16(v.y);
        h.z = to_bf16(v.z); h.w = to_bf16(v.w);
        *reinterpret_cast<ushort4*>(&lds[slot * kSlot + 26 * kKP + c4]) = h;
    }
    __syncthreads();

    // ---- Each wave computes one batch: C = X * X^T (32x32 padded), tiles C00, C01, C11 (C10 = C01^T skipped)
    const int wave = t >> 6;
    const int lane = t & 63;
    const short* X = &lds[wave * kSlot];
    const int m    = lane & 15;    // A/B fragment row (M or N index)
    const int quad = lane >> 4;    // k-group

    f32x4 c00 = {0.f, 0.f, 0.f, 0.f};
    f32x4 c01 = {0.f, 0.f, 0.f, 0.f};
    f32x4 c11 = {0.f, 0.f, 0.f, 0.f};

    #pragma unroll
    for (int k0 = 0; k0 < kD; k0 += 32) {
        // A-fragment: lane holds X[m][k0 + quad*8 + 0..7]; identical layout serves as B-fragment (B^T = X)
        bf16x8 a0 = *reinterpret_cast<const bf16x8*>(&X[m * kKP + quad * 8 + k0]);          // rows 0-15
        bf16x8 a1 = *reinterpret_cast<const bf16x8*>(&X[(16 + m) * kKP + quad * 8 + k0]);   // rows 16-31
        c00 = __builtin_amdgcn_mfma_f32_16x16x32_bf16(a0, a0, c00, 0, 0, 0);
        c01 = __builtin_amdgcn_mfma_f32_16x16x32_bf16(a0, a1, c01, 0, 0, 0);
        c11 = __builtin_amdgcn_mfma_f32_16x16x32_bf16(a1, a1, c11, 0, 0, 0);
    }

    // ---- Epilogue: C/D layout col = lane&15, row = quad*4 + reg  [measured m89/m91]
    float* ob = out + (size_t)(b0 + wave) * kPairs;
    const int j = m;
    #pragma unroll
    for (int r = 0; r < 4; ++r) {
        const int i = quad * 4 + r;
        if (i < j)                        ob[triu_idx(i, j)]           = c00[r];  // 120 pairs
        if (16 + j < kRows)               ob[triu_idx(i, 16 + j)]      = c01[r];  // 176 pairs (i<16<=j always)
        if (i < j && 16 + j < kRows)      ob[triu_idx(16 + i, 16 + j)] = c11[r];  // 55 pairs
    }
}

extern "C" void kernel_launch(void* const* d_in, const int* in_sizes, int n_in,
                              void* d_out, int out_size, void* d_ws, size_t ws_size,
                              hipStream_t stream) {
    const float* sparse_x = (const float*)d_in[0];
    const float* dense_x  = (const float*)d_in[1];
    float* out = (float*)d_out;
    const int B = in_sizes[1] / kD;             // 16384
    interact_kernel<<<B / kNB, 256, 0, stream>>>(sparse_x, dense_x, out);
}